// Round 3
// baseline (194.223 us; speedup 1.0000x reference)
//
#include <hip/hip_runtime.h>

// Problem constants (from reference setup_inputs)
#define BB  8
#define PP  16384
#define KK  16384
#define NN  16
#define CIN 64
#define REL 3
#define CC  67          // CIN + REL
#define OUTC 64
#define WTOT (OUTC * CC) // 4288 floats = 17152 B LDS

// One wave per 8 consecutive k within ONE batch. b = blockIdx & 7 so the
// round-robin blockIdx->XCD dispatch binds each XCD to one batch: its 4MB L2
// holds exactly that batch's 4MB feats slab -> random gathers hit L2.
//
// Round-3 fixes vs round 2 (94us):
//  * W row pinned in VGPRs. Round 2's VGPR_Count=48 (<67) proved the compiler
//    folded wreg back into 67 ds_read_b32 PER ROW -> ~83us of DS-pipe time
//    chip-wide (512 rows/CU x 67 x 5.8cyc). The asm memory clobber after the
//    fill forbids sinking the LDS loads into the loop.
//  * XCD<->batch binding (above) to cut FETCH_SIZE 255MB -> ~100MB.
//  * unroll 2 on the row loop: next row's gathers issue under this row's
//    readlane/dot chain.
__global__ __launch_bounds__(256, 4) void graphconv_kernel(
    const float* __restrict__ feats,         // [B, P, CIN]
    const int*   __restrict__ n_idxs,        // [B, K, N]
    const float* __restrict__ neighbor_rel,  // [B, K, N, REL]
    const int*   __restrict__ neighbor_valid,// [B, K, N]
    const float* __restrict__ Wm,            // [OUTC, CC]
    const float* __restrict__ bvec,          // [OUTC]
    float*       __restrict__ out)           // [B, K, OUTC]
{
    __shared__ float lds_w[WTOT];
    for (int i = threadIdx.x; i < WTOT; i += 256) lds_w[i] = Wm[i];
    __syncthreads();

    const int lane = threadIdx.x & 63;
    const int wave = __builtin_amdgcn_readfirstlane((int)(threadIdx.x >> 6));
    const int b    = blockIdx.x & 7;          // XCD-bound batch
    const int bib  = blockIdx.x >> 3;         // block index within batch
    const int k0   = (bib * 4 + wave) * 8;    // 8 consecutive k per wave

    // Per-lane W row for output channel `lane`. Bank-conflict-free fill:
    // (lane*67+c)%32 = (3*lane+c)%32 covers all banks, 2 lanes/bank = free.
    float wreg[CC];
#pragma unroll
    for (int c = 0; c < CC; ++c) wreg[c] = lds_w[lane * CC + c];
    const float bias = bvec[lane];
    // Pin wreg/bias in VGPRs: memory clobber forbids re-materializing the
    // LDS reads inside the row loop (round-2 failure mode).
    asm volatile("" ::: "memory");

    const float* fb = feats + (size_t)b * ((size_t)PP * CIN);

#pragma unroll 2
    for (int i = 0; i < 8; ++i) {
        const int    k    = k0 + i;
        const size_t row  = (size_t)b * KK + (size_t)k;
        const int*   idxp = n_idxs         + row * NN;       // uniform
        const int*   vp   = neighbor_valid + row * NN;       // uniform
        const float* relp = neighbor_rel   + row * (NN * REL); // uniform

        float sum = 0.0f;                    // per-lane channel sum
        float r0 = 0.0f, r1 = 0.0f, r2 = 0.0f;
        int count = 0;
#pragma unroll
        for (int n = 0; n < NN; ++n) {
            const int   v  = vp[n];          // uniform s_load, no branch
            const int   id = idxp[n];        // uniform s_load
            const float m  = (float)v;
            // s_base + s(id*256) + v(lane*4): scalar addressing, coalesced 256B
            const float g  = fb[(size_t)id * CIN + lane];
            sum = fmaf(m, g, sum);
            r0  = fmaf(m, relp[n * 3 + 0], r0);
            r1  = fmaf(m, relp[n * 3 + 1], r1);
            r2  = fmaf(m, relp[n * 3 + 2], r2);
            count += v;
        }

        const float inv = (count > 0) ? (1.0f / (float)count) : 0.0f;

        // lane o: dot_c scaled[c]*W[o][c]; channel sums broadcast via
        // v_readlane, 4 accumulators break the FMA dependence chain.
        float d0 = 0.0f, d1 = 0.0f, d2 = 0.0f, d3 = 0.0f;
#pragma unroll
        for (int c = 0; c < CIN; c += 4) {
            const float s0 = __int_as_float(
                __builtin_amdgcn_readlane(__float_as_int(sum), c + 0));
            const float s1 = __int_as_float(
                __builtin_amdgcn_readlane(__float_as_int(sum), c + 1));
            const float s2 = __int_as_float(
                __builtin_amdgcn_readlane(__float_as_int(sum), c + 2));
            const float s3 = __int_as_float(
                __builtin_amdgcn_readlane(__float_as_int(sum), c + 3));
            d0 = fmaf(s0, wreg[c + 0], d0);
            d1 = fmaf(s1, wreg[c + 1], d1);
            d2 = fmaf(s2, wreg[c + 2], d2);
            d3 = fmaf(s3, wreg[c + 3], d3);
        }
        d0 = fmaf(r0, wreg[CIN + 0], d0);
        d1 = fmaf(r1, wreg[CIN + 1], d1);
        d2 = fmaf(r2, wreg[CIN + 2], d2);
        const float dot = (d0 + d1) + (d2 + d3);

        const float o = fmaf(dot, inv, bias);    // inv folded past the dot
        out[row * OUTC + lane] = fmaxf(o, 0.0f); // coalesced 256B store
    }
}

extern "C" void kernel_launch(void* const* d_in, const int* in_sizes, int n_in,
                              void* d_out, int out_size, void* d_ws, size_t ws_size,
                              hipStream_t stream) {
    // setup_inputs order: keys(0), points(1), feats(2), n_idxs(3),
    // neighbor_rel(4), neighbor_valid(5), W(6), b(7). keys/points unused.
    const float* feats = (const float*)d_in[2];
    const int*   nidx  = (const int*)  d_in[3];
    const float* nrel  = (const float*)d_in[4];
    const int*   nval  = (const int*)  d_in[5];
    const float* Wm    = (const float*)d_in[6];
    const float* bv    = (const float*)d_in[7];
    float* out = (float*)d_out;

    // 4096 blocks: 512 per batch x 8 batches (b = blockIdx & 7 -> XCD binding).
    // 4 waves/block x 8 rows/wave x 512 blocks = 16384 k per batch.
    graphconv_kernel<<<dim3(4096), dim3(256), 0, stream>>>(
        feats, nidx, nrel, nval, Wm, bv, out);
}

// Round 4
// 186.691 us; speedup vs baseline: 1.0403x; 1.0403x over previous
//
#include <hip/hip_runtime.h>

// Problem constants (from reference setup_inputs)
#define BB  8
#define PP  16384
#define KK  16384
#define NN  16
#define CIN 64
#define REL 3
#define CC  67          // CIN + REL
#define OUTC 64
#define WTOT (OUTC * CC) // 4288 floats = 17152 B LDS

// One wave per 8 consecutive k within ONE batch. b = blockIdx & 7: the
// round-robin blockIdx->XCD dispatch binds each XCD to one batch, so its 4MB
// L2 holds exactly that batch's 4MB feats slab (verified: FETCH 255->109MB).
//
// Round-4 fix vs round 3 (96us): rounds 2+3 were DS-pipe-bound -- the
// compiler sank the wreg fill back into the row loop as 67 ds_read_b32 PER
// ROW (VGPR_Count=52 < 67 proved it; 512 rows/CU x 67 x 5.8cyc = 83us).
// The generic `asm volatile("":::"memory")` clobber did NOT stop it (LLVM
// treats LDS separately). Fix: tie every loaded W element to a VGPR with
// an opaque `asm("" : "+v"(w))` -- the value is unknown after the asm, so
// re-reading LDS is illegal and wreg must stay register-resident.
// Also: dropped unroll-2 (live-state pressure) and widened the VGPR cap via
// __launch_bounds__(256,3) so the allocator doesn't spill the pinned regs.
__global__ __launch_bounds__(256, 3) void graphconv_kernel(
    const float* __restrict__ feats,         // [B, P, CIN]
    const int*   __restrict__ n_idxs,        // [B, K, N]
    const float* __restrict__ neighbor_rel,  // [B, K, N, REL]
    const int*   __restrict__ neighbor_valid,// [B, K, N]
    const float* __restrict__ Wm,            // [OUTC, CC]
    const float* __restrict__ bvec,          // [OUTC]
    float*       __restrict__ out)           // [B, K, OUTC]
{
    __shared__ float lds_w[WTOT];
    for (int i = threadIdx.x; i < WTOT; i += 256) lds_w[i] = Wm[i];
    __syncthreads();

    const int lane = threadIdx.x & 63;
    const int wave = __builtin_amdgcn_readfirstlane((int)(threadIdx.x >> 6));
    const int b    = blockIdx.x & 7;          // XCD-bound batch
    const int bib  = blockIdx.x >> 3;         // block index within batch
    const int k0   = (bib * 4 + wave) * 8;    // 8 consecutive k per wave

    // Per-lane W row for out-channel `lane`, PINNED in VGPRs (see header).
    float wreg[CC];
#pragma unroll
    for (int c = 0; c < CC; ++c) {
        float w = lds_w[lane * CC + c];   // stride-67 dwords: 2 lanes/bank, free
        asm("" : "+v"(w));                // opaque: must stay in a VGPR
        wreg[c] = w;
    }
    const float bias = bvec[lane];

    const float* fb = feats + (size_t)b * ((size_t)PP * CIN);

    for (int i = 0; i < 8; ++i) {
        const int    k    = k0 + i;
        const size_t row  = (size_t)b * KK + (size_t)k;
        const int*   idxp = n_idxs         + row * NN;         // uniform
        const int*   vp   = neighbor_valid + row * NN;         // uniform
        const float* relp = neighbor_rel   + row * (NN * REL); // uniform

        float sum = 0.0f;                    // per-lane channel sum
        float r0 = 0.0f, r1 = 0.0f, r2 = 0.0f;
        int count = 0;
#pragma unroll
        for (int n = 0; n < NN; ++n) {
            const int   v  = vp[n];          // uniform s_load, no branch
            const int   id = idxp[n];        // uniform s_load
            const float m  = (float)v;
            // s_base + s(id*256) + v(lane*4): coalesced 256B gather
            const float g  = fb[(size_t)id * CIN + lane];
            sum = fmaf(m, g, sum);
            r0  = fmaf(m, relp[n * 3 + 0], r0);
            r1  = fmaf(m, relp[n * 3 + 1], r1);
            r2  = fmaf(m, relp[n * 3 + 2], r2);
            count += v;
        }

        const float inv = (count > 0) ? (1.0f / (float)count) : 0.0f;

        // lane o: dot_c scaled[c]*W[o][c]; channel sums broadcast via
        // v_readlane, 4 accumulators break the FMA dependence chain.
        float d0 = 0.0f, d1 = 0.0f, d2 = 0.0f, d3 = 0.0f;
#pragma unroll
        for (int c = 0; c < CIN; c += 4) {
            const float s0 = __int_as_float(
                __builtin_amdgcn_readlane(__float_as_int(sum), c + 0));
            const float s1 = __int_as_float(
                __builtin_amdgcn_readlane(__float_as_int(sum), c + 1));
            const float s2 = __int_as_float(
                __builtin_amdgcn_readlane(__float_as_int(sum), c + 2));
            const float s3 = __int_as_float(
                __builtin_amdgcn_readlane(__float_as_int(sum), c + 3));
            d0 = fmaf(s0, wreg[c + 0], d0);
            d1 = fmaf(s1, wreg[c + 1], d1);
            d2 = fmaf(s2, wreg[c + 2], d2);
            d3 = fmaf(s3, wreg[c + 3], d3);
        }
        d0 = fmaf(r0, wreg[CIN + 0], d0);
        d1 = fmaf(r1, wreg[CIN + 1], d1);
        d2 = fmaf(r2, wreg[CIN + 2], d2);
        const float dot = (d0 + d1) + (d2 + d3);

        const float o = fmaf(dot, inv, bias);    // inv folded past the dot
        out[row * OUTC + lane] = fmaxf(o, 0.0f); // coalesced 256B store
    }
}

extern "C" void kernel_launch(void* const* d_in, const int* in_sizes, int n_in,
                              void* d_out, int out_size, void* d_ws, size_t ws_size,
                              hipStream_t stream) {
    // setup_inputs order: keys(0), points(1), feats(2), n_idxs(3),
    // neighbor_rel(4), neighbor_valid(5), W(6), b(7). keys/points unused.
    const float* feats = (const float*)d_in[2];
    const int*   nidx  = (const int*)  d_in[3];
    const float* nrel  = (const float*)d_in[4];
    const int*   nval  = (const int*)  d_in[5];
    const float* Wm    = (const float*)d_in[6];
    const float* bv    = (const float*)d_in[7];
    float* out = (float*)d_out;

    // 4096 blocks: 512 per batch x 8 batches (b = blockIdx & 7 -> XCD binding).
    // 4 waves/block x 8 rows/wave x 512 blocks = 16384 k per batch.
    graphconv_kernel<<<dim3(4096), dim3(256), 0, stream>>>(
        feats, nidx, nrel, nval, Wm, bv, out);
}

// Round 5
// 173.792 us; speedup vs baseline: 1.1176x; 1.0742x over previous
//
#include <hip/hip_runtime.h>

// Problem constants (from reference setup_inputs)
#define BB   8
#define PP   16384
#define KK   16384
#define NN   16
#define CIN  64
#define REL  3
#define CC   67            // CIN + REL
#define OUTC 64
#define KPAD 96            // MFMA K dim: 64 feat + 3 rel + 29 zero pad
#define PITCH_US 104       // ushorts per LDS row: 96 data + 8 pad = 208 B
                           // = 52 dwords; odd x4 -> b128 reads conflict-free
#define GPW  2             // row-groups (of 16) per wave

// Rounds 2-4 all plateaued at ~94us: the compiler kept re-sinking the 67-
// element W row into 67 ds_read_b32 PER ROW (VGPR_Count 48<67 every round;
// 512 rows/CU x 67 x 5.8cyc = 83us DS-pipe = the plateau). Round-4's asm pin
// failed because it lacked `volatile` (pure asm is rematerializable).
//
// Round 5 removes the need for 67 pinned regs + 128 readlane/fma per row:
// the matvec scaled[rows,67] x W^T[67,64] goes to the (idle) MFMA pipe.
//  * W -> bf16 once per block into LDS in B-operand-friendly layout
//    [o][k0..95], cols 67..95 zeroed (kills pad garbage: A*0=0).
//  * Each wave stages 16 rows of scaled sums as bf16 into a WAVE-PRIVATE
//    LDS tile (lane=channel, ds_write_b16; no __syncthreads needed).
//  * 3 ds_read_b128 A-frags + 12 v_mfma_f32_16x16x32_bf16 per 16 rows.
//  * B-frags (48 VGPRs) pinned with asm VOLATILE tied constraints.
// Precision: bf16 in / fp32 accum -> ~1e-2 worst case vs 7.25e-2 threshold.
// Keeps the round-3 XCD<->batch binding (FETCH 255->109MB, verified).

typedef short s16x8 __attribute__((ext_vector_type(8)));   // 8 bf16 = 4 VGPRs
typedef float f32x4 __attribute__((ext_vector_type(4)));   // MFMA accum

static __device__ __forceinline__ unsigned short bf16_rne(float f) {
    unsigned int u = __float_as_uint(f);
    u += 0x7FFF + ((u >> 16) & 1);          // round-to-nearest-even
    return (unsigned short)(u >> 16);
}

__global__ __launch_bounds__(256, 4) void graphconv_kernel(
    const float* __restrict__ feats,         // [B, P, CIN]
    const int*   __restrict__ n_idxs,        // [B, K, N]
    const float* __restrict__ neighbor_rel,  // [B, K, N, REL]
    const int*   __restrict__ neighbor_valid,// [B, K, N]
    const float* __restrict__ Wm,            // [OUTC, CC]
    const float* __restrict__ bvec,          // [OUTC]
    float*       __restrict__ out)           // [B, K, OUTC]
{
    // bf16 W image, B-layout: Wbf[o][k], k=0..66 = W[o][k], 67.. = 0
    __shared__ __align__(16) unsigned short Wbf[OUTC * PITCH_US];   // 13312 B
    // per-wave 16-row staging tiles (wave-private -> no barriers)
    __shared__ __align__(16) unsigned short Stile[4 * 16 * PITCH_US]; // 13312 B

    const int tid = threadIdx.x;

    // ---- one-time: W -> bf16 into LDS (dword writes, 2 cols each) ----
    {
        unsigned int* w32 = (unsigned int*)Wbf;
        for (int j = tid; j < OUTC * (PITCH_US / 2); j += 256) {
            const int o = j / (PITCH_US / 2);
            const int d = j - o * (PITCH_US / 2);
            const int c0 = 2 * d, c1 = 2 * d + 1;
            const float w0 = (c0 < CC) ? Wm[o * CC + c0] : 0.0f;
            const float w1 = (c1 < CC) ? Wm[o * CC + c1] : 0.0f;
            w32[j] = (unsigned int)bf16_rne(w0) |
                     ((unsigned int)bf16_rne(w1) << 16);
        }
    }
    __syncthreads();

    const int lane = tid & 63;
    const int wave = __builtin_amdgcn_readfirstlane(tid >> 6);
    unsigned short* Sw = &Stile[wave * 16 * PITCH_US];

    // zero own tile once (pad cols 67..95 must be 0.0, not NaN garbage)
    {
        unsigned int* s32 = (unsigned int*)Sw;
        for (int j = lane; j < 16 * (PITCH_US / 2); j += 64) s32[j] = 0u;
    }

    // ---- B-frags: B[k][n], lane n=lane&15, k=q*32+(lane>>4)*8+j ----
    // Wbf row stride 52 dwords: bank (3n + k/2)%32-ish pattern, 16B reads
    // spread evenly over 8 bank phases -> conflict-free.
    s16x8 Bfr[4][3];
#pragma unroll
    for (int t = 0; t < 4; ++t)
#pragma unroll
        for (int q = 0; q < 3; ++q) {
            s16x8 v = *(const s16x8*)&Wbf[(t * 16 + (lane & 15)) * PITCH_US
                                          + q * 32 + (lane >> 4) * 8];
            asm volatile("" : "+v"(v));   // VOLATILE: cannot remat/sink
            Bfr[t][q] = v;
        }
    float bias_t[4];
#pragma unroll
    for (int t = 0; t < 4; ++t) bias_t[t] = bvec[t * 16 + (lane & 15)];

    const int b   = blockIdx.x & 7;          // XCD-bound batch (verified win)
    const int bib = blockIdx.x >> 3;         // block index within batch
    const float* fb = feats + (size_t)b * ((size_t)PP * CIN);

    for (int g = 0; g < GPW; ++g) {
        const int kbase = ((bib * 4 + wave) * GPW + g) * 16;

        // ---- phase 1: gather+masked-sum 16 rows -> bf16 LDS tile ----
        for (int i = 0; i < 16; ++i) {
            const size_t row  = (size_t)b * KK + (size_t)(kbase + i);
            const int*   idxp = n_idxs         + row * NN;         // uniform
            const int*   vp   = neighbor_valid + row * NN;         // uniform
            const float* relp = neighbor_rel   + row * (NN * REL); // uniform

            float sum = 0.0f, r0 = 0.0f, r1 = 0.0f, r2 = 0.0f;
            int count = 0;
#pragma unroll
            for (int n = 0; n < NN; ++n) {
                const int   v  = vp[n];      // uniform s_load, branchless
                const int   id = idxp[n];    // uniform s_load
                const float m  = (float)v;
                const float gv = fb[(size_t)id * CIN + lane]; // 256B gather
                sum = fmaf(m, gv, sum);
                r0  = fmaf(m, relp[n * 3 + 0], r0);
                r1  = fmaf(m, relp[n * 3 + 1], r1);
                r2  = fmaf(m, relp[n * 3 + 2], r2);
                count += v;
            }
            const float inv = (count > 0) ? (1.0f / (float)count) : 0.0f;

            Sw[i * PITCH_US + lane] = bf16_rne(sum * inv);  // lane=channel
            if (lane < 3) {                                  // rel -> ch 64..66
                const float rv = (lane == 0) ? r0 : ((lane == 1) ? r1 : r2);
                Sw[i * PITCH_US + 64 + lane] = bf16_rne(rv * inv);
            }
        }

        // ---- phase 2: 16x64 = S(16x96) x W^T(96x64) on MFMA pipe ----
        f32x4 C0 = {0.f,0.f,0.f,0.f}, C1 = {0.f,0.f,0.f,0.f};
        f32x4 C2 = {0.f,0.f,0.f,0.f}, C3 = {0.f,0.f,0.f,0.f};
#pragma unroll
        for (int q = 0; q < 3; ++q) {
            // A[m][k]: m=lane&15, k=q*32+(lane>>4)*8+j  (16B aligned read)
            const s16x8 A = *(const s16x8*)&Sw[(lane & 15) * PITCH_US
                                               + q * 32 + (lane >> 4) * 8];
            C0 = __builtin_amdgcn_mfma_f32_16x16x32_bf16(A, Bfr[0][q], C0, 0, 0, 0);
            C1 = __builtin_amdgcn_mfma_f32_16x16x32_bf16(A, Bfr[1][q], C1, 0, 0, 0);
            C2 = __builtin_amdgcn_mfma_f32_16x16x32_bf16(A, Bfr[2][q], C2, 0, 0, 0);
            C3 = __builtin_amdgcn_mfma_f32_16x16x32_bf16(A, Bfr[3][q], C3, 0, 0, 0);
        }

        // ---- epilogue: C/D layout col=lane&15 (=outch%16), row=(lane>>4)*4+r
        const int m0 = (lane >> 4) * 4;
        const int oc = lane & 15;
#pragma unroll
        for (int r = 0; r < 4; ++r) {
            const size_t orow = ((size_t)b * KK + (size_t)(kbase + m0 + r)) * OUTC;
            out[orow + 0  + oc] = fmaxf(C0[r] + bias_t[0], 0.0f);
            out[orow + 16 + oc] = fmaxf(C1[r] + bias_t[1], 0.0f);
            out[orow + 32 + oc] = fmaxf(C2[r] + bias_t[2], 0.0f);
            out[orow + 48 + oc] = fmaxf(C3[r] + bias_t[3], 0.0f);
        }
    }
}

extern "C" void kernel_launch(void* const* d_in, const int* in_sizes, int n_in,
                              void* d_out, int out_size, void* d_ws, size_t ws_size,
                              hipStream_t stream) {
    // setup_inputs order: keys(0), points(1), feats(2), n_idxs(3),
    // neighbor_rel(4), neighbor_valid(5), W(6), b(7). keys/points unused.
    const float* feats = (const float*)d_in[2];
    const int*   nidx  = (const int*)  d_in[3];
    const float* nrel  = (const float*)d_in[4];
    const int*   nval  = (const int*)  d_in[5];
    const float* Wm    = (const float*)d_in[6];
    const float* bv    = (const float*)d_in[7];
    float* out = (float*)d_out;

    // 1024 blocks = 128 per batch (b = blockIdx&7 -> XCD binding).
    // 4 waves/block x 2 groups x 16 rows = 128 rows/block; 128*128 = 16384 k.
    // 4 blocks/CU x 4 waves = 16 waves/CU at <=128 VGPR (launch_bounds 256,4).
    graphconv_kernel<<<dim3(1024), dim3(256), 0, stream>>>(
        feats, nidx, nrel, nval, Wm, bv, out);
}